// Round 1
// 642.384 us; speedup vs baseline: 1.0008x; 1.0008x over previous
//
#include <hip/hip_runtime.h>
#include <math.h>

// Problem constants (from reference: z (32,4096,256) f32, embed (1024,256) f32)
#define N_TOK   131072
#define DIM     256
#define K_CODE  1024
#define KEXT    768       // extended K: [zh,zh,zl] x [ch,cl,ch]
#define MARGIN  2e-3f     // top1-top2 gap (||z||-scaled units) below which we redo in fp64
                          // computation error std ~3.5e-5 -> 57 sigma; flags ~0.5% of tokens

// Workspace layout (bytes)
#define WS_COUNTS   0         // 1024 * int      (histogram)
#define WS_LOSS     4096      // double          (sum of squared diffs)
#define WS_RCOUNT   4104      // int             (recheck-list count)
#define WS_INVN     8192      // 1024 * float    (1/||c_k||)
#define WS_FIDX     16384     // N_TOK * int     (final argmax index per token)
#define WS_RLIST    1048576   // N_TOK * int     (tokens needing fp64 recheck)
#define WS_BEXT     2097152   // 1024*768 bf16 = 1.5 MB packed codebook (LDS image layout)

#define CHUNK_BYTES 49152     // 32 codes x 768 x 2B, one LDS chunk image

// Output layout (floats): z_q_st[33554432], loss, perplexity, indices[131072]
#define OUT_LOSS  33554432
#define OUT_PERP  33554433
#define OUT_IDX   33554434

typedef __bf16 bf16x8 __attribute__((ext_vector_type(8)));
typedef float  f32x4  __attribute__((ext_vector_type(4)));

// round-to-nearest-even fp32 -> bf16 bits
static __device__ __forceinline__ unsigned short f2bf(float f) {
    unsigned int u = __float_as_uint(f);
    u += 0x7FFFu + ((u >> 16) & 1u);
    return (unsigned short)(u >> 16);
}
static __device__ __forceinline__ float bf2f(unsigned short h) {
    return __uint_as_float(((unsigned int)h) << 16);
}

// async global->LDS, 16B per lane; LDS dest = wave-uniform base + lane*16
static __device__ __forceinline__ void load_lds16(const void* g, void* l) {
    __builtin_amdgcn_global_load_lds(
        (const __attribute__((address_space(1))) unsigned int*)g,
        (__attribute__((address_space(3))) unsigned int*)l, 16, 0, 0);
}

// ---------------------------------------------------------------- Phase A ---
// inv_norm[k] = 1/max(||c_k||,eps). One wave per code.
__global__ void vq_norms(const float* __restrict__ embed, float* __restrict__ invn) {
    int lane = threadIdx.x & 63;
    int wave = (blockIdx.x * blockDim.x + threadIdx.x) >> 6;
    int nwav = (gridDim.x * blockDim.x) >> 6;
    for (int k = wave; k < K_CODE; k += nwav) {
        float4 v = *(const float4*)&embed[k * DIM + lane * 4];
        float s = v.x * v.x + v.y * v.y + v.z * v.z + v.w * v.w;
        #pragma unroll
        for (int off = 32; off; off >>= 1) s += __shfl_xor(s, off);
        if (lane == 0) invn[k] = 1.0f / fmaxf(sqrtf(s), 1e-12f);
    }
}

// ---------------------------------------------------------------- Phase A2 --
// Pack B_ext: per code k, K-dim kk in [0,768): kk<256 -> bf16hi(c[kk]),
// kk<512 -> bf16lo(c[kk-256]), else bf16hi(c[kk-512]). Layout is the exact
// per-chunk LDS image: chunk c (32 codes) is 48 KB of
// [nt(2)][ks24(24)][quad(4)][col(16)][j(8)] bf16, so global_load_lds can
// stage it as 1 KB/wave-inst contiguous segments, and ds_read_b128 at
// lane*16 yields the MFMA B-fragment (B[n=lane&15][k=quad*8+j]) directly.
// One thread per (k, kk/8): 1024*96 = 98304 threads.
__global__ void vq_pack(const float* __restrict__ embed, unsigned short* __restrict__ bext) {
    int id = blockIdx.x * 256 + threadIdx.x;
    int k   = id / 96;
    int j8  = id - k * 96;
    int kk0 = j8 * 8;
    int src, hi;
    if (kk0 < 256)      { src = kk0;       hi = 1; }
    else if (kk0 < 512) { src = kk0 - 256; hi = 0; }
    else                { src = kk0 - 512; hi = 1; }
    const float* e = &embed[k * DIM + src];
    float4 f0 = *(const float4*)e;
    float4 f1 = *(const float4*)(e + 4);
    float v[8] = {f0.x, f0.y, f0.z, f0.w, f1.x, f1.y, f1.z, f1.w};
    unsigned short r[8] __attribute__((aligned(16)));
    #pragma unroll
    for (int j = 0; j < 8; ++j) {
        unsigned short h = f2bf(v[j]);
        r[j] = hi ? h : f2bf(v[j] - bf2f(h));
    }
    int c = k >> 5, kin = k & 31;
    int nt = kin >> 4, col = kin & 15;
    int ks = kk0 >> 5, quad = (kk0 >> 3) & 3;
    size_t dst = (size_t)c * CHUNK_BYTES + (size_t)(((nt * 24 + ks) * 64) + quad * 16 + col) * 16;
    *(float4*)((char*)bext + dst) = *(const float4*)r;
}

// ---------------------------------------------------------------- Phase B ---
// MFMA argmax GEMM, K=768 ([zh,zh,zl] . [ch,cl,ch]), T3+T4+T5 schedule.
// Block: 256 tokens (8 waves x 2 m-tiles), all 1024 codes in 32 chunks of 32.
// Double-buffered 48 KB chunk images (b0/b1), prefetch issued one chunk ahead
// via global_load_lds; COUNTED s_waitcnt vmcnt(6) at the top of each chunk
// (own outstanding = 6 of chunk c + 6 of chunk c+1 -> vmcnt(6) proves c is
// landed without draining c+1); raw s_barrier (no __syncthreads -> no
// compiler-forced vmcnt(0) drain); setprio(1) around the MFMA cluster.
// invn is preloaded to LDS so the loop body issues ZERO vmem ops outside
// staging -> vmcnt FIFO arithmetic stays exact.
__launch_bounds__(512, 2)
__global__ void vq_argmax(const float* __restrict__ z,
                          const unsigned short* __restrict__ bext,
                          const float* __restrict__ invn, int* __restrict__ fidx,
                          int* __restrict__ rcount, int* __restrict__ rlist) {
    __shared__ unsigned short b0[CHUNK_BYTES / 2];      // 48 KB
    __shared__ unsigned short b1[CHUNK_BYTES / 2];      // 48 KB
    __shared__ float invn_s[K_CODE];                    // 4 KB

    const int tid  = threadIdx.x;
    const int w    = tid >> 6;          // 8 waves
    const int lane = tid & 63;
    const int col  = lane & 15;
    const int quad = lane >> 4;
    const int tokBase = blockIdx.x * 256;

    // invn -> LDS (visibility: lgkmcnt(0) here + the barrier at loop top)
    invn_s[tid]       = invn[tid];
    invn_s[tid + 512] = invn[tid + 512];
    asm volatile("s_waitcnt lgkmcnt(0)" ::: "memory");

    // ---- A fragments: wave w owns tokens [w*32, w*32+32). Per m-tile (16
    // rows): zh/zl frags for 8 k-steps of 32. A[m=lane&15][k=quad*8+j].
    bf16x8 ah[2][8], al[2][8];
    #pragma unroll
    for (int mt = 0; mt < 2; ++mt) {
        const float* zr = z + (size_t)(tokBase + w * 32 + mt * 16 + col) * DIM;
        #pragma unroll
        for (int ks = 0; ks < 8; ++ks) {
            float4 f0 = *(const float4*)(zr + ks * 32 + quad * 8);
            float4 f1 = *(const float4*)(zr + ks * 32 + quad * 8 + 4);
            float v[8] = {f0.x, f0.y, f0.z, f0.w, f1.x, f1.y, f1.z, f1.w};
            union { bf16x8 v; unsigned short u[8]; } th, tl;
            #pragma unroll
            for (int j = 0; j < 8; ++j) {
                unsigned short h = f2bf(v[j]);
                th.u[j] = h;
                tl.u[j] = f2bf(v[j] - bf2f(h));
            }
            ah[mt][ks] = th.v;
            al[mt][ks] = tl.v;
        }
    }

    // per-wave staging: 48 segs of 1 KB per chunk / 8 waves = 6 segs/wave
    auto stage = [&](int c, unsigned short* buf) {
        const char* gsrc = (const char*)bext + (size_t)c * CHUNK_BYTES;
        #pragma unroll
        for (int i = 0; i < 6; ++i) {
            int seg = w * 6 + i;
            load_lds16(gsrc + (size_t)seg * 1024 + lane * 16,
                       (char*)buf + seg * 1024);
        }
    };

    float best[2][4], second[2][4];
    int   bidx[2][4];
    #pragma unroll
    for (int mt = 0; mt < 2; ++mt)
        #pragma unroll
        for (int r = 0; r < 4; ++r) { best[mt][r] = -1e30f; second[mt][r] = -1e30f; bidx[mt][r] = 0; }

    auto compute = [&](int c, const unsigned short* bbuf) {
        f32x4 acc[2][2];
        #pragma unroll
        for (int mt = 0; mt < 2; ++mt)
            #pragma unroll
            for (int nt = 0; nt < 2; ++nt) acc[mt][nt] = (f32x4){0.f, 0.f, 0.f, 0.f};

        __builtin_amdgcn_s_setprio(1);
        #pragma unroll
        for (int nt = 0; nt < 2; ++nt) {
            const unsigned short* bb = bbuf + nt * 24 * 512;   // ushort index
            #pragma unroll
            for (int ks = 0; ks < 8; ++ks) {   // zh . ch
                bf16x8 b = *(const bf16x8*)&bb[ks * 512 + lane * 8];
                acc[0][nt] = __builtin_amdgcn_mfma_f32_16x16x32_bf16(ah[0][ks], b, acc[0][nt], 0, 0, 0);
                acc[1][nt] = __builtin_amdgcn_mfma_f32_16x16x32_bf16(ah[1][ks], b, acc[1][nt], 0, 0, 0);
            }
            #pragma unroll
            for (int ks = 0; ks < 8; ++ks) {   // zh . cl
                bf16x8 b = *(const bf16x8*)&bb[(8 + ks) * 512 + lane * 8];
                acc[0][nt] = __builtin_amdgcn_mfma_f32_16x16x32_bf16(ah[0][ks], b, acc[0][nt], 0, 0, 0);
                acc[1][nt] = __builtin_amdgcn_mfma_f32_16x16x32_bf16(ah[1][ks], b, acc[1][nt], 0, 0, 0);
            }
            #pragma unroll
            for (int ks = 0; ks < 8; ++ks) {   // zl . ch
                bf16x8 b = *(const bf16x8*)&bb[(16 + ks) * 512 + lane * 8];
                acc[0][nt] = __builtin_amdgcn_mfma_f32_16x16x32_bf16(al[0][ks], b, acc[0][nt], 0, 0, 0);
                acc[1][nt] = __builtin_amdgcn_mfma_f32_16x16x32_bf16(al[1][ks], b, acc[1][nt], 0, 0, 0);
            }
        }
        __builtin_amdgcn_s_setprio(0);

        // epilogue: scale by inv||c|| (from LDS), per-thread top-2.
        #pragma unroll
        for (int nt = 0; nt < 2; ++nt) {
            int code = c * 32 + nt * 16 + col;
            float iv = invn_s[code];
            #pragma unroll
            for (int mt = 0; mt < 2; ++mt)
                #pragma unroll
                for (int r = 0; r < 4; ++r) {
                    float v = acc[mt][nt][r] * iv;
                    if (v > best[mt][r]) { second[mt][r] = best[mt][r]; best[mt][r] = v; bidx[mt][r] = code; }
                    else                 { second[mt][r] = fmaxf(second[mt][r], v); }
                }
        }
    };

    // prologue: keep A-loads strictly before staging (vmcnt FIFO invariant)
    __builtin_amdgcn_sched_barrier(0);
    stage(0, b0);
    stage(1, b1);

    // steady state at top of chunk c: own outstanding = stage(c)[6] + stage(c+1)[6]
    //   -> vmcnt(6) <=> chunk c fully landed (FIFO). Last chunk: vmcnt(0).
    #pragma unroll 1
    for (int cc = 0; cc < 32; cc += 2) {
        // ---- even chunk (b0) ----
        asm volatile("s_waitcnt vmcnt(6)" ::: "memory");
        __builtin_amdgcn_s_barrier();
        __builtin_amdgcn_sched_barrier(0);
        compute(cc, b0);
        __builtin_amdgcn_sched_barrier(0);
        __builtin_amdgcn_s_barrier();          // all waves done reading b0
        if (cc + 2 < 32) stage(cc + 2, b0);    // prefetch flies during compute(cc+1)

        // ---- odd chunk (b1) ----
        if (cc == 30) { asm volatile("s_waitcnt vmcnt(0)" ::: "memory"); }
        else          { asm volatile("s_waitcnt vmcnt(6)" ::: "memory"); }
        __builtin_amdgcn_s_barrier();
        __builtin_amdgcn_sched_barrier(0);
        compute(cc + 1, b1);
        __builtin_amdgcn_sched_barrier(0);
        __builtin_amdgcn_s_barrier();          // all waves done reading b1
        if (cc + 3 < 32) stage(cc + 3, b1);
    }

    // Merge top-2 across the 16 D-columns (disjoint code sets per lane).
    #pragma unroll
    for (int mt = 0; mt < 2; ++mt)
        #pragma unroll
        for (int r = 0; r < 4; ++r) {
            float B = best[mt][r], S = second[mt][r];
            int   I = bidx[mt][r];
            #pragma unroll
            for (int off = 1; off < 16; off <<= 1) {
                float ob = __shfl_xor(B, off);
                float os = __shfl_xor(S, off);
                int   oi = __shfl_xor(I, off);
                if (ob > B) {
                    S = fmaxf(B, os);
                    B = ob; I = oi;
                } else {
                    if (ob == B && oi < I) I = oi;   // tie: first occurrence
                    S = fmaxf(S, ob);                // ob==B -> gap 0 -> recheck
                }
            }
            if (col == 0) {
                int token = tokBase + w * 32 + mt * 16 + quad * 4 + r;   // D row = quad*4+reg
                fidx[token] = I;
                if (B - S < MARGIN) {
                    int p = atomicAdd(rcount, 1);
                    rlist[p] = token;
                }
            }
        }
}

// ---------------------------------------------------------------- Phase R ---
// Exact fp64 argmax for flagged tokens (full scan of all 1024 codes).
__global__ void vq_recheck(const float* __restrict__ z, const float* __restrict__ embed,
                           const int* __restrict__ rcount, const int* __restrict__ rlist,
                           int* __restrict__ fidx) {
    __shared__ double zd[DIM];
    __shared__ double rv[256];
    __shared__ int    rix[256];
    const int cnt = *rcount;
    for (int li = blockIdx.x; li < cnt; li += gridDim.x) {
        int token = rlist[li];
        __syncthreads();
        zd[threadIdx.x] = (double)z[token * DIM + threadIdx.x];
        __syncthreads();
        double bv = -1e300;
        int    bi = 0;
        #pragma unroll
        for (int j = 0; j < 4; ++j) {
            int k = threadIdx.x * 4 + j;   // ascending per thread
            const float* e = &embed[k * DIM];
            double acc = 0.0, nrm = 0.0;
            for (int d = 0; d < DIM; d += 4) {
                float4 ef = *(const float4*)&e[d];
                acc += (double)ef.x * zd[d]     + (double)ef.y * zd[d + 1] +
                       (double)ef.z * zd[d + 2] + (double)ef.w * zd[d + 3];
                nrm += (double)ef.x * ef.x + (double)ef.y * ef.y +
                       (double)ef.z * ef.z + (double)ef.w * ef.w;
            }
            double val = acc / fmax(sqrt(nrm), 1e-12);   // 1/||z|| scale dropped
            if (val > bv) { bv = val; bi = k; }
        }
        rv[threadIdx.x]  = bv;
        rix[threadIdx.x] = bi;
        __syncthreads();
        for (int s = 128; s; s >>= 1) {
            if (threadIdx.x < s) {
                double v2 = rv[threadIdx.x + s];
                int    i2 = rix[threadIdx.x + s];
                if (v2 > rv[threadIdx.x] ||
                    (v2 == rv[threadIdx.x] && i2 < rix[threadIdx.x])) {
                    rv[threadIdx.x] = v2;
                    rix[threadIdx.x] = i2;
                }
            }
            __syncthreads();
        }
        if (threadIdx.x == 0) fidx[token] = rix[0];
    }
}

// ---------------------------------------------------------------- Phase C ---
// Gather z_q, write z_q_st = z + (z_q - z) (fp32, mimics straight-through),
// accumulate sum((z_q - z)^2) in double, histogram counts, write index floats.
__global__ void vq_output(const float* __restrict__ z, const float* __restrict__ embed,
                          const int* __restrict__ fidx, float* __restrict__ out,
                          int* __restrict__ counts, double* __restrict__ lossAcc) {
    int lane = threadIdx.x & 63;
    int gw   = (blockIdx.x * blockDim.x + threadIdx.x) >> 6;
    int nwav = (gridDim.x * blockDim.x) >> 6;
    double lsum = 0.0;
    for (int t = gw; t < N_TOK; t += nwav) {
        int idx = fidx[t];
        float4 e  = *(const float4*)&embed[idx * DIM + lane * 4];
        float4 zz = *(const float4*)&z[(size_t)t * DIM + lane * 4];
        float4 r, o;
        r.x = e.x - zz.x; r.y = e.y - zz.y; r.z = e.z - zz.z; r.w = e.w - zz.w;
        o.x = zz.x + r.x; o.y = zz.y + r.y; o.z = zz.z + r.z; o.w = zz.w + r.w;
        *(float4*)&out[(size_t)t * DIM + lane * 4] = o;
        lsum += (double)r.x * r.x + (double)r.y * r.y +
                (double)r.z * r.z + (double)r.w * r.w;
        if (lane == 0) {
            atomicAdd(&counts[idx], 1);
            out[OUT_IDX + t] = (float)idx;
        }
    }
    #pragma unroll
    for (int off = 32; off; off >>= 1) lsum += __shfl_down(lsum, off);
    if (lane == 0) atomicAdd(lossAcc, lsum);
}

// ---------------------------------------------------------------- Phase D ---
__global__ void vq_finalize(const int* __restrict__ counts,
                            const double* __restrict__ lossAcc,
                            float* __restrict__ out) {
    __shared__ double sh[256];
    double s = 0.0;
    for (int b = threadIdx.x; b < K_CODE; b += 256) {
        double p = (double)counts[b] / (double)N_TOK;
        s += p * log(p + 1e-10);   // p==0 contributes exactly 0
    }
    sh[threadIdx.x] = s;
    __syncthreads();
    for (int st = 128; st; st >>= 1) {
        if (threadIdx.x < st) sh[threadIdx.x] += sh[threadIdx.x + st];
        __syncthreads();
    }
    if (threadIdx.x == 0) {
        out[OUT_PERP] = (float)exp(-sh[0]);
        out[OUT_LOSS] = (float)(1.25 * (*lossAcc) / (double)(N_TOK) / (double)(DIM));
    }
}

// ----------------------------------------------------------------- launch ---
extern "C" void kernel_launch(void* const* d_in, const int* in_sizes, int n_in,
                              void* d_out, int out_size, void* d_ws, size_t ws_size,
                              hipStream_t stream) {
    const float* z     = (const float*)d_in[0];
    const float* embed = (const float*)d_in[1];
    float* out = (float*)d_out;
    char*  ws  = (char*)d_ws;

    int*            counts  = (int*)   (ws + WS_COUNTS);
    double*         lossAcc = (double*)(ws + WS_LOSS);
    int*            rcount  = (int*)   (ws + WS_RCOUNT);
    float*          invn    = (float*) (ws + WS_INVN);
    int*            fidx    = (int*)   (ws + WS_FIDX);
    int*            rlist   = (int*)   (ws + WS_RLIST);
    unsigned short* bext    = (unsigned short*)(ws + WS_BEXT);

    // zero counts / loss accumulator / recheck count (ws is poisoned 0xAA)
    hipMemsetAsync(ws, 0, 16384, stream);

    vq_norms  <<<16,   256, 0, stream>>>(embed, invn);
    vq_pack   <<<384,  256, 0, stream>>>(embed, bext);
    vq_argmax <<<N_TOK / 256, 512, 0, stream>>>(z, bext, invn, fidx, rcount, rlist);
    vq_recheck<<<512,  256, 0, stream>>>(z, embed, rcount, rlist, fidx);
    vq_output <<<2048, 256, 0, stream>>>(z, embed, fidx, out, counts, lossAcc);
    vq_finalize<<<1,   256, 0, stream>>>(counts, lossAcc, out);
}